// Round 1
// baseline (655.869 us; speedup 1.0000x reference)
//
#include <hip/hip_runtime.h>

#define N_TOK   8192
#define TOPK    2
#define N_EXP   8
#define DM      1024
#define DFF     2048
#define CAP     3072

typedef __attribute__((ext_vector_type(8))) short bf16x8;
typedef __attribute__((ext_vector_type(4))) float f32x4;

__device__ __forceinline__ unsigned short f2bf(float x) {
    union { float f; unsigned u; } un; un.f = x;
    unsigned r = un.u + 0x7fffu + ((un.u >> 16) & 1u);
    return (unsigned short)(r >> 16);
}

__device__ __forceinline__ void glds16(const void* g, void* l) {
    __builtin_amdgcn_global_load_lds(
        (const __attribute__((address_space(1))) unsigned int*)g,
        (__attribute__((address_space(3))) unsigned int*)l, 16, 0, 0);
}

// ---- x fp32 -> bf16 ----
__global__ void cvt_x_kernel(const float4* __restrict__ x, ushort4* __restrict__ xb) {
    int i = blockIdx.x * 256 + threadIdx.x;
    float4 v = x[i];
    ushort4 o;
    o.x = f2bf(v.x); o.y = f2bf(v.y); o.z = f2bf(v.z); o.w = f2bf(v.w);
    xb[i] = o;
}

// ---- transpose + convert: in [E][R][C] fp32 -> out [E][C][R] bf16 ----
__global__ void transpose_cvt_kernel(const float* __restrict__ in, unsigned short* __restrict__ out,
                                     int R, int C) {
    __shared__ float tile[32][33];
    const int e = blockIdx.z;
    const int r0 = blockIdx.y * 32, c0 = blockIdx.x * 32;
    const float* src = in + ((size_t)e * R + r0) * C + c0;
    const int tx = threadIdx.x, ty = threadIdx.y;
#pragma unroll
    for (int i = 0; i < 4; i++)
        tile[ty + 8 * i][tx] = src[(size_t)(ty + 8 * i) * C + tx];
    __syncthreads();
    unsigned short* dst = out + ((size_t)e * C + c0) * R + r0;
#pragma unroll
    for (int i = 0; i < 4; i++) {
        int c = ty + 8 * i;
        dst[(size_t)c * R + tx] = f2bf(tile[tx][c]);
    }
}

// ---- dispatch: slot assignment per (token, k) ----
__global__ void dispatch_kernel(const int* __restrict__ eidx, const float* __restrict__ ewt,
                                int* __restrict__ counts, int* __restrict__ row_token,
                                float* __restrict__ row_weight) {
    int i = blockIdx.x * 256 + threadIdx.x;
    if (i < N_TOK * TOPK) {
        int e = eidx[i];
        int pos = atomicAdd(&counts[e], 1);
        if (pos < CAP) {
            row_token[e * CAP + pos] = i >> 1;   // TOPK == 2
            row_weight[e * CAP + pos] = ewt[i];
        }
    }
}

// ---- GEMM1: gate/value fused, silu*mul epilogue -> hidden bf16 ----
// A: gathered xb rows [M=128][K=1024]; B1/B2: w1t/w2t [E][2048 f][1024 d] bf16 (K-contig)
__global__ __launch_bounds__(256, 2)
void gemm1_kernel(const unsigned short* __restrict__ xb, const unsigned short* __restrict__ w1t,
                  const unsigned short* __restrict__ w2t, const int* __restrict__ counts,
                  const int* __restrict__ row_token, unsigned short* __restrict__ hidden) {
    const int e = blockIdx.z;
    const int r0 = blockIdx.y * 128;
    if (r0 >= counts[e]) return;
    const int f0 = blockIdx.x * 128;

    __shared__ unsigned short lA[128 * 32];
    __shared__ unsigned short lB1[128 * 32];
    __shared__ unsigned short lB2[128 * 32];

    const int t = threadIdx.x;
    const int lane = t & 63;
    const int wave = t >> 6;

    // staging: thread covers row (t>>2) and row+64, byte chunk (t&3)*16 of the 64B row
    const int rstage = t >> 2;
    const int kbyte = (t & 3) * 16;

    const int tok0 = row_token[e * CAP + r0 + rstage];
    const int tok1 = row_token[e * CAP + r0 + 64 + rstage];
    const char* pA0 = (const char*)(xb + (size_t)tok0 * DM) + kbyte;
    const char* pA1 = (const char*)(xb + (size_t)tok1 * DM) + kbyte;
    const char* pB1a = (const char*)(w1t + ((size_t)e * DFF + f0 + rstage) * DM) + kbyte;
    const char* pB1b = pB1a + (size_t)64 * DM * 2;
    const char* pB2a = (const char*)(w2t + ((size_t)e * DFF + f0 + rstage) * DM) + kbyte;
    const char* pB2b = pB2a + (size_t)64 * DM * 2;

    char* lAp = (char*)lA + t * 16;
    char* lB1p = (char*)lB1 + t * 16;
    char* lB2p = (char*)lB2 + t * 16;

    const int mw = (wave & 1) * 64;
    const int nw = (wave >> 1) * 64;
    const int l15 = lane & 15;
    const int lq = lane >> 4;
    const unsigned short* aBase = lA + (mw + l15) * 32 + lq * 8;
    const unsigned short* b1Base = lB1 + (nw + l15) * 32 + lq * 8;
    const unsigned short* b2Base = lB2 + (nw + l15) * 32 + lq * 8;

    f32x4 accG[4][4];
    f32x4 accV[4][4];
#pragma unroll
    for (int i = 0; i < 4; i++)
#pragma unroll
        for (int j = 0; j < 4; j++) {
            accG[i][j] = (f32x4){0.f, 0.f, 0.f, 0.f};
            accV[i][j] = (f32x4){0.f, 0.f, 0.f, 0.f};
        }

    for (int k0 = 0; k0 < DM; k0 += 32) {
        glds16(pA0, lAp);            glds16(pA1, lAp + 4096);
        glds16(pB1a, lB1p);          glds16(pB1b, lB1p + 4096);
        glds16(pB2a, lB2p);          glds16(pB2b, lB2p + 4096);
        pA0 += 64; pA1 += 64; pB1a += 64; pB1b += 64; pB2a += 64; pB2b += 64;
        __syncthreads();

        bf16x8 a[4], b1[4], b2[4];
#pragma unroll
        for (int i = 0; i < 4; i++) {
            a[i]  = *(const bf16x8*)(aBase  + i * 512);
            b1[i] = *(const bf16x8*)(b1Base + i * 512);
            b2[i] = *(const bf16x8*)(b2Base + i * 512);
        }
#pragma unroll
        for (int i = 0; i < 4; i++)
#pragma unroll
            for (int j = 0; j < 4; j++) {
                accG[i][j] = __builtin_amdgcn_mfma_f32_16x16x32_bf16(a[i], b1[j], accG[i][j], 0, 0, 0);
                accV[i][j] = __builtin_amdgcn_mfma_f32_16x16x32_bf16(a[i], b2[j], accV[i][j], 0, 0, 0);
            }
        __syncthreads();
    }

    // epilogue: hidden = silu(gate) * value, stored bf16
    const size_t hbase = ((size_t)e * CAP + r0) * DFF + f0;
#pragma unroll
    for (int i = 0; i < 4; i++)
#pragma unroll
        for (int j = 0; j < 4; j++)
#pragma unroll
            for (int r = 0; r < 4; r++) {
                int m = mw + i * 16 + lq * 4 + r;
                int n = nw + j * 16 + l15;
                float g = accG[i][j][r];
                float v = accV[i][j][r];
                float h = (g / (1.f + __expf(-g))) * v;
                hidden[hbase + (size_t)m * DFF + n] = f2bf(h);
            }
}

// ---- GEMM2: out_rows = hidden @ w3^T, weighted atomic scatter into d_out ----
__global__ __launch_bounds__(256, 2)
void gemm2_kernel(const unsigned short* __restrict__ hidden, const unsigned short* __restrict__ w3t,
                  const int* __restrict__ counts, const int* __restrict__ row_token,
                  const float* __restrict__ row_weight, float* __restrict__ out) {
    const int e = blockIdx.z;
    const int r0 = blockIdx.y * 128;
    if (r0 >= counts[e]) return;
    const int d0 = blockIdx.x * 128;

    __shared__ unsigned short lA[128 * 32];
    __shared__ unsigned short lB[128 * 32];

    const int t = threadIdx.x;
    const int lane = t & 63;
    const int wave = t >> 6;

    const int rstage = t >> 2;
    const int kbyte = (t & 3) * 16;

    const char* pA0 = (const char*)(hidden + ((size_t)e * CAP + r0 + rstage) * DFF) + kbyte;
    const char* pA1 = pA0 + (size_t)64 * DFF * 2;
    const char* pB0 = (const char*)(w3t + ((size_t)e * DM + d0 + rstage) * DFF) + kbyte;
    const char* pB1 = pB0 + (size_t)64 * DFF * 2;

    char* lAp = (char*)lA + t * 16;
    char* lBp = (char*)lB + t * 16;

    const int mw = (wave & 1) * 64;
    const int nw = (wave >> 1) * 64;
    const int l15 = lane & 15;
    const int lq = lane >> 4;
    const unsigned short* aBase = lA + (mw + l15) * 32 + lq * 8;
    const unsigned short* bBase = lB + (nw + l15) * 32 + lq * 8;

    f32x4 acc[4][4];
#pragma unroll
    for (int i = 0; i < 4; i++)
#pragma unroll
        for (int j = 0; j < 4; j++) acc[i][j] = (f32x4){0.f, 0.f, 0.f, 0.f};

    for (int k0 = 0; k0 < DFF; k0 += 32) {
        glds16(pA0, lAp);  glds16(pA1, lAp + 4096);
        glds16(pB0, lBp);  glds16(pB1, lBp + 4096);
        pA0 += 64; pA1 += 64; pB0 += 64; pB1 += 64;
        __syncthreads();

        bf16x8 a[4], b[4];
#pragma unroll
        for (int i = 0; i < 4; i++) {
            a[i] = *(const bf16x8*)(aBase + i * 512);
            b[i] = *(const bf16x8*)(bBase + i * 512);
        }
#pragma unroll
        for (int i = 0; i < 4; i++)
#pragma unroll
            for (int j = 0; j < 4; j++)
                acc[i][j] = __builtin_amdgcn_mfma_f32_16x16x32_bf16(a[i], b[j], acc[i][j], 0, 0, 0);
        __syncthreads();
    }

    const float* rw = row_weight + e * CAP + r0;
    const int* rt = row_token + e * CAP + r0;
#pragma unroll
    for (int i = 0; i < 4; i++)
#pragma unroll
        for (int r = 0; r < 4; r++) {
            int m = mw + i * 16 + lq * 4 + r;
            float w = rw[m];
            if (w != 0.f) {
                int tok = rt[m];
                float* orow = out + (size_t)tok * DM + d0 + nw + l15;
#pragma unroll
                for (int j = 0; j < 4; j++)
                    atomicAdd(orow + j * 16, acc[i][j][r] * w);
            }
        }
}

extern "C" void kernel_launch(void* const* d_in, const int* in_sizes, int n_in,
                              void* d_out, int out_size, void* d_ws, size_t ws_size,
                              hipStream_t stream) {
    const float* x = (const float*)d_in[0];
    const int* eidx = (const int*)d_in[1];
    const float* ewt = (const float*)d_in[2];
    const float* w1 = (const float*)d_in[3];
    const float* w2 = (const float*)d_in[4];
    const float* w3 = (const float*)d_in[5];
    float* out = (float*)d_out;

    char* ws = (char*)d_ws;
    size_t off = 0;
    auto alloc = [&](size_t b) { size_t o = off; off += (b + 255) & ~(size_t)255; return o; };
    int*   counts     = (int*)(ws + alloc(N_EXP * 4));
    int*   row_token  = (int*)(ws + alloc((size_t)N_EXP * CAP * 4));
    float* row_weight = (float*)(ws + alloc((size_t)N_EXP * CAP * 4));
    size_t hdr_end = off;
    unsigned short* xb  = (unsigned short*)(ws + alloc((size_t)N_TOK * DM * 2));
    unsigned short* w1t = (unsigned short*)(ws + alloc((size_t)N_EXP * DFF * DM * 2));
    unsigned short* w2t = (unsigned short*)(ws + alloc((size_t)N_EXP * DFF * DM * 2));
    unsigned short* w3t = (unsigned short*)(ws + alloc((size_t)N_EXP * DM * DFF * 2));
    unsigned short* hidden = (unsigned short*)(ws + alloc((size_t)N_EXP * CAP * DFF * 2));
    (void)ws_size; (void)in_sizes; (void)n_in;

    hipMemsetAsync(d_out, 0, (size_t)out_size * sizeof(float), stream);
    hipMemsetAsync(ws, 0, hdr_end, stream);  // counts + row_token + row_weight

    cvt_x_kernel<<<(N_TOK * DM / 4) / 256, 256, 0, stream>>>((const float4*)x, (ushort4*)xb);
    transpose_cvt_kernel<<<dim3(DFF / 32, DM / 32, N_EXP), dim3(32, 8), 0, stream>>>(w1, w1t, DM, DFF);
    transpose_cvt_kernel<<<dim3(DFF / 32, DM / 32, N_EXP), dim3(32, 8), 0, stream>>>(w2, w2t, DM, DFF);
    transpose_cvt_kernel<<<dim3(DM / 32, DFF / 32, N_EXP), dim3(32, 8), 0, stream>>>(w3, w3t, DFF, DM);
    dispatch_kernel<<<(N_TOK * TOPK) / 256, 256, 0, stream>>>(eidx, ewt, counts, row_token, row_weight);

    gemm1_kernel<<<dim3(DFF / 128, CAP / 128, N_EXP), 256, 0, stream>>>(xb, w1t, w2t, counts, row_token, hidden);
    gemm2_kernel<<<dim3(DM / 128, CAP / 128, N_EXP), 256, 0, stream>>>(hidden, w3t, counts, row_token, row_weight, out);
}

// Round 2
// 641.843 us; speedup vs baseline: 1.0219x; 1.0219x over previous
//
#include <hip/hip_runtime.h>

#define N_TOK   8192
#define TOPK    2
#define N_EXP   8
#define DM      1024
#define DFF     2048
#define CAP     3072

typedef __attribute__((ext_vector_type(8))) short bf16x8;
typedef __attribute__((ext_vector_type(4))) float f32x4;

__device__ __forceinline__ unsigned short f2bf(float x) {
    union { float f; unsigned u; } un; un.f = x;
    unsigned r = un.u + 0x7fffu + ((un.u >> 16) & 1u);
    return (unsigned short)(r >> 16);
}

__device__ __forceinline__ void glds16(const void* g, void* l) {
    __builtin_amdgcn_global_load_lds(
        (const __attribute__((address_space(1))) unsigned int*)g,
        (__attribute__((address_space(3))) unsigned int*)l, 16, 0, 0);
}

// ---- x fp32 -> bf16 ----
__global__ void cvt_x_kernel(const float4* __restrict__ x, ushort4* __restrict__ xb) {
    int i = blockIdx.x * 256 + threadIdx.x;
    float4 v = x[i];
    ushort4 o;
    o.x = f2bf(v.x); o.y = f2bf(v.y); o.z = f2bf(v.z); o.w = f2bf(v.w);
    xb[i] = o;
}

// ---- transpose + convert, 64x64 tiles: in [E][R][C] fp32 -> out [E][C][R] bf16 ----
// z<8 uses inA/outA (expert z), z>=8 uses inB/outB (expert z-8).
__global__ void transpose_cvt64_kernel(const float* __restrict__ inA, const float* __restrict__ inB,
                                       unsigned short* __restrict__ outA, unsigned short* __restrict__ outB,
                                       int R, int C) {
    __shared__ unsigned short L[64][72];
    const int z = blockIdx.z;
    const float* in = (z & 8) ? inB : inA;
    unsigned short* out = (z & 8) ? outB : outA;
    const int e = z & 7;
    const int r0 = blockIdx.y * 64, c0 = blockIdx.x * 64;
    const int t = threadIdx.x;
    const int rr = t >> 4;       // 0..15
    const int cv = t & 15;       // float4 col index
    const float4* src = (const float4*)(in + ((size_t)e * R + r0) * C + c0);
    const int c4 = C >> 2;
#pragma unroll
    for (int i = 0; i < 4; i++) {
        int r = rr + 16 * i;
        float4 v = src[(size_t)r * c4 + cv];
        L[r][cv * 4 + 0] = f2bf(v.x);
        L[r][cv * 4 + 1] = f2bf(v.y);
        L[r][cv * 4 + 2] = f2bf(v.z);
        L[r][cv * 4 + 3] = f2bf(v.w);
    }
    __syncthreads();
    unsigned short* dst = out + ((size_t)e * C + c0) * R + r0;
    const int cc = t >> 4;       // 0..15
    const int rv = t & 15;       // ushort4 along r
#pragma unroll
    for (int i = 0; i < 4; i++) {
        int c = cc + 16 * i;
        ushort4 o;
        o.x = L[rv * 4 + 0][c];
        o.y = L[rv * 4 + 1][c];
        o.z = L[rv * 4 + 2][c];
        o.w = L[rv * 4 + 3][c];
        *(ushort4*)(dst + (size_t)c * R + rv * 4) = o;
    }
}

// ---- dispatch: slot assignment per (token, k) ----
__global__ void dispatch_kernel(const int* __restrict__ eidx, const float* __restrict__ ewt,
                                int* __restrict__ counts, int* __restrict__ row_token,
                                float* __restrict__ row_weight) {
    int i = blockIdx.x * 256 + threadIdx.x;
    if (i < N_TOK * TOPK) {
        int e = eidx[i];
        int pos = atomicAdd(&counts[e], 1);
        if (pos < CAP) {
            row_token[e * CAP + pos] = i >> 1;   // TOPK == 2
            row_weight[e * CAP + pos] = ewt[i];
        }
    }
}

// ---- GEMM1: gate/value fused, silu*mul epilogue -> hidden bf16 ----
__global__ __launch_bounds__(256, 2)
void gemm1_kernel(const unsigned short* __restrict__ xb, const unsigned short* __restrict__ w1t,
                  const unsigned short* __restrict__ w2t, const int* __restrict__ counts,
                  const int* __restrict__ row_token, unsigned short* __restrict__ hidden) {
    const int e = blockIdx.z;
    const int r0 = blockIdx.y * 128;
    if (r0 >= counts[e]) return;
    const int f0 = blockIdx.x * 128;

    __shared__ unsigned short lA[128 * 32];
    __shared__ unsigned short lB1[128 * 32];
    __shared__ unsigned short lB2[128 * 32];

    const int t = threadIdx.x;
    const int lane = t & 63;
    const int wave = t >> 6;

    // staging: thread covers row (t>>2) and row+64; global chunk is XOR-swizzled
    const int rstage = t >> 2;
    const int cs = (t & 3) ^ ((rstage >> 1) & 3);   // swizzled source chunk
    const int kbyte = cs * 16;

    const int tok0 = row_token[e * CAP + r0 + rstage];
    const int tok1 = row_token[e * CAP + r0 + 64 + rstage];
    const char* pA0 = (const char*)(xb + (size_t)tok0 * DM) + kbyte;
    const char* pA1 = (const char*)(xb + (size_t)tok1 * DM) + kbyte;
    const char* pB1a = (const char*)(w1t + ((size_t)e * DFF + f0 + rstage) * DM) + kbyte;
    const char* pB1b = pB1a + (size_t)64 * DM * 2;
    const char* pB2a = (const char*)(w2t + ((size_t)e * DFF + f0 + rstage) * DM) + kbyte;
    const char* pB2b = pB2a + (size_t)64 * DM * 2;

    char* lAp = (char*)lA + t * 16;
    char* lB1p = (char*)lB1 + t * 16;
    char* lB2p = (char*)lB2 + t * 16;

    const int mw = (wave & 1) * 64;
    const int nw = (wave >> 1) * 64;
    const int l15 = lane & 15;
    const int lq = lane >> 4;
    const int swz = (l15 >> 1) & 3;                 // row-derived swizzle selector
    const unsigned short* aBase  = lA  + (mw + l15) * 32 + ((lq ^ swz) * 8);
    const unsigned short* b1Base = lB1 + (nw + l15) * 32 + ((lq ^ swz) * 8);
    const unsigned short* b2Base = lB2 + (nw + l15) * 32 + ((lq ^ swz) * 8);

    f32x4 accG[4][4];
    f32x4 accV[4][4];
#pragma unroll
    for (int i = 0; i < 4; i++)
#pragma unroll
        for (int j = 0; j < 4; j++) {
            accG[i][j] = (f32x4){0.f, 0.f, 0.f, 0.f};
            accV[i][j] = (f32x4){0.f, 0.f, 0.f, 0.f};
        }

    for (int k0 = 0; k0 < DM; k0 += 32) {
        glds16(pA0, lAp);            glds16(pA1, lAp + 4096);
        glds16(pB1a, lB1p);          glds16(pB1b, lB1p + 4096);
        glds16(pB2a, lB2p);          glds16(pB2b, lB2p + 4096);
        pA0 += 64; pA1 += 64; pB1a += 64; pB1b += 64; pB2a += 64; pB2b += 64;
        __syncthreads();

        bf16x8 a[4], b1[4], b2[4];
#pragma unroll
        for (int i = 0; i < 4; i++) {
            a[i]  = *(const bf16x8*)(aBase  + i * 512);
            b1[i] = *(const bf16x8*)(b1Base + i * 512);
            b2[i] = *(const bf16x8*)(b2Base + i * 512);
        }
#pragma unroll
        for (int i = 0; i < 4; i++)
#pragma unroll
            for (int j = 0; j < 4; j++) {
                accG[i][j] = __builtin_amdgcn_mfma_f32_16x16x32_bf16(a[i], b1[j], accG[i][j], 0, 0, 0);
                accV[i][j] = __builtin_amdgcn_mfma_f32_16x16x32_bf16(a[i], b2[j], accV[i][j], 0, 0, 0);
            }
        __syncthreads();
    }

    // epilogue: hidden = silu(gate) * value, stored bf16
    const size_t hbase = ((size_t)e * CAP + r0) * DFF + f0;
#pragma unroll
    for (int i = 0; i < 4; i++)
#pragma unroll
        for (int j = 0; j < 4; j++)
#pragma unroll
            for (int r = 0; r < 4; r++) {
                int m = mw + i * 16 + lq * 4 + r;
                int n = nw + j * 16 + l15;
                float g = accG[i][j][r];
                float v = accV[i][j][r];
                float h = (g / (1.f + __expf(-g))) * v;
                hidden[hbase + (size_t)m * DFF + n] = f2bf(h);
            }
}

// ---- GEMM2: out_rows = hidden @ w3^T, weighted atomic scatter into d_out ----
__global__ __launch_bounds__(256, 2)
void gemm2_kernel(const unsigned short* __restrict__ hidden, const unsigned short* __restrict__ w3t,
                  const int* __restrict__ counts, const int* __restrict__ row_token,
                  const float* __restrict__ row_weight, float* __restrict__ out) {
    const int e = blockIdx.z;
    const int r0 = blockIdx.y * 128;
    if (r0 >= counts[e]) return;
    const int d0 = blockIdx.x * 128;

    __shared__ unsigned short lA[128 * 32];
    __shared__ unsigned short lB[128 * 32];

    const int t = threadIdx.x;
    const int lane = t & 63;
    const int wave = t >> 6;

    const int rstage = t >> 2;
    const int cs = (t & 3) ^ ((rstage >> 1) & 3);
    const int kbyte = cs * 16;

    const char* pA0 = (const char*)(hidden + ((size_t)e * CAP + r0 + rstage) * DFF) + kbyte;
    const char* pA1 = pA0 + (size_t)64 * DFF * 2;
    const char* pB0 = (const char*)(w3t + ((size_t)e * DM + d0 + rstage) * DFF) + kbyte;
    const char* pB1 = pB0 + (size_t)64 * DFF * 2;

    char* lAp = (char*)lA + t * 16;
    char* lBp = (char*)lB + t * 16;

    const int mw = (wave & 1) * 64;
    const int nw = (wave >> 1) * 64;
    const int l15 = lane & 15;
    const int lq = lane >> 4;
    const int swz = (l15 >> 1) & 3;
    const unsigned short* aBase = lA + (mw + l15) * 32 + ((lq ^ swz) * 8);
    const unsigned short* bBase = lB + (nw + l15) * 32 + ((lq ^ swz) * 8);

    f32x4 acc[4][4];
#pragma unroll
    for (int i = 0; i < 4; i++)
#pragma unroll
        for (int j = 0; j < 4; j++) acc[i][j] = (f32x4){0.f, 0.f, 0.f, 0.f};

    for (int k0 = 0; k0 < DFF; k0 += 32) {
        glds16(pA0, lAp);  glds16(pA1, lAp + 4096);
        glds16(pB0, lBp);  glds16(pB1, lBp + 4096);
        pA0 += 64; pA1 += 64; pB0 += 64; pB1 += 64;
        __syncthreads();

        bf16x8 a[4], b[4];
#pragma unroll
        for (int i = 0; i < 4; i++) {
            a[i] = *(const bf16x8*)(aBase + i * 512);
            b[i] = *(const bf16x8*)(bBase + i * 512);
        }
#pragma unroll
        for (int i = 0; i < 4; i++)
#pragma unroll
            for (int j = 0; j < 4; j++)
                acc[i][j] = __builtin_amdgcn_mfma_f32_16x16x32_bf16(a[i], b[j], acc[i][j], 0, 0, 0);
        __syncthreads();
    }

    const float* rw = row_weight + e * CAP + r0;
    const int* rt = row_token + e * CAP + r0;
#pragma unroll
    for (int i = 0; i < 4; i++)
#pragma unroll
        for (int r = 0; r < 4; r++) {
            int m = mw + i * 16 + lq * 4 + r;
            float w = rw[m];
            if (w != 0.f) {
                int tok = rt[m];
                float* orow = out + (size_t)tok * DM + d0 + nw + l15;
#pragma unroll
                for (int j = 0; j < 4; j++)
                    atomicAdd(orow + j * 16, acc[i][j][r] * w);
            }
        }
}

extern "C" void kernel_launch(void* const* d_in, const int* in_sizes, int n_in,
                              void* d_out, int out_size, void* d_ws, size_t ws_size,
                              hipStream_t stream) {
    const float* x = (const float*)d_in[0];
    const int* eidx = (const int*)d_in[1];
    const float* ewt = (const float*)d_in[2];
    const float* w1 = (const float*)d_in[3];
    const float* w2 = (const float*)d_in[4];
    const float* w3 = (const float*)d_in[5];
    float* out = (float*)d_out;

    char* ws = (char*)d_ws;
    size_t off = 0;
    auto alloc = [&](size_t b) { size_t o = off; off += (b + 255) & ~(size_t)255; return o; };
    int*   counts     = (int*)(ws + alloc(N_EXP * 4));
    int*   row_token  = (int*)(ws + alloc((size_t)N_EXP * CAP * 4));
    float* row_weight = (float*)(ws + alloc((size_t)N_EXP * CAP * 4));
    size_t hdr_end = off;
    unsigned short* xb  = (unsigned short*)(ws + alloc((size_t)N_TOK * DM * 2));
    unsigned short* w1t = (unsigned short*)(ws + alloc((size_t)N_EXP * DFF * DM * 2));
    unsigned short* w2t = (unsigned short*)(ws + alloc((size_t)N_EXP * DFF * DM * 2));
    unsigned short* w3t = (unsigned short*)(ws + alloc((size_t)N_EXP * DM * DFF * 2));
    unsigned short* hidden = (unsigned short*)(ws + alloc((size_t)N_EXP * CAP * DFF * 2));
    (void)ws_size; (void)in_sizes; (void)n_in;

    hipMemsetAsync(d_out, 0, (size_t)out_size * sizeof(float), stream);
    hipMemsetAsync(ws, 0, hdr_end, stream);  // counts + row_token + row_weight

    cvt_x_kernel<<<(N_TOK * DM / 4) / 256, 256, 0, stream>>>((const float4*)x, (ushort4*)xb);
    // w1 + w2 fused in one launch (z<8 -> w1, z>=8 -> w2): in [E][DM][DFF] -> out [E][DFF][DM]
    transpose_cvt64_kernel<<<dim3(DFF / 64, DM / 64, 16), 256, 0, stream>>>(w1, w2, w1t, w2t, DM, DFF);
    // w3: in [E][DFF][DM] -> out [E][DM][DFF]
    transpose_cvt64_kernel<<<dim3(DM / 64, DFF / 64, 8), 256, 0, stream>>>(w3, w3, w3t, w3t, DFF, DM);
    dispatch_kernel<<<(N_TOK * TOPK) / 256, 256, 0, stream>>>(eidx, ewt, counts, row_token, row_weight);

    gemm1_kernel<<<dim3(DFF / 128, CAP / 128, N_EXP), 256, 0, stream>>>(xb, w1t, w2t, counts, row_token, hidden);
    gemm2_kernel<<<dim3(DM / 128, CAP / 128, N_EXP), 256, 0, stream>>>(hidden, w3t, counts, row_token, row_weight, out);
}

// Round 3
// 594.633 us; speedup vs baseline: 1.1030x; 1.0794x over previous
//
#include <hip/hip_runtime.h>

#define N_TOK   8192
#define TOPK    2
#define N_EXP   8
#define DM      1024
#define DFF     2048
#define CAP     3072

typedef __attribute__((ext_vector_type(8))) short bf16x8;
typedef __attribute__((ext_vector_type(4))) float f32x4;

__device__ __forceinline__ unsigned short f2bf(float x) {
    union { float f; unsigned u; } un; un.f = x;
    unsigned r = un.u + 0x7fffu + ((un.u >> 16) & 1u);
    return (unsigned short)(r >> 16);
}
__device__ __forceinline__ float bf2f(unsigned short u) {
    union { unsigned u; float f; } c; c.u = ((unsigned)u) << 16; return c.f;
}

__device__ __forceinline__ void glds16(const void* g, void* l) {
    __builtin_amdgcn_global_load_lds(
        (const __attribute__((address_space(1))) unsigned int*)g,
        (__attribute__((address_space(3))) unsigned int*)l, 16, 0, 0);
}

// ---- x fp32 -> bf16 ----
__global__ void cvt_x_kernel(const float4* __restrict__ x, ushort4* __restrict__ xb) {
    int i = blockIdx.x * 256 + threadIdx.x;
    float4 v = x[i];
    ushort4 o;
    o.x = f2bf(v.x); o.y = f2bf(v.y); o.z = f2bf(v.z); o.w = f2bf(v.w);
    xb[i] = o;
}

// ---- transpose + convert, 64x64 tiles: in [E][R][C] fp32 -> out [E][C][R] bf16 ----
__global__ void transpose_cvt64_kernel(const float* __restrict__ inA, const float* __restrict__ inB,
                                       unsigned short* __restrict__ outA, unsigned short* __restrict__ outB,
                                       int R, int C) {
    __shared__ unsigned short L[64][72];
    const int z = blockIdx.z;
    const float* in = (z & 8) ? inB : inA;
    unsigned short* out = (z & 8) ? outB : outA;
    const int e = z & 7;
    const int r0 = blockIdx.y * 64, c0 = blockIdx.x * 64;
    const int t = threadIdx.x;
    const int rr = t >> 4;
    const int cv = t & 15;
    const float4* src = (const float4*)(in + ((size_t)e * R + r0) * C + c0);
    const int c4 = C >> 2;
#pragma unroll
    for (int i = 0; i < 4; i++) {
        int r = rr + 16 * i;
        float4 v = src[(size_t)r * c4 + cv];
        L[r][cv * 4 + 0] = f2bf(v.x);
        L[r][cv * 4 + 1] = f2bf(v.y);
        L[r][cv * 4 + 2] = f2bf(v.z);
        L[r][cv * 4 + 3] = f2bf(v.w);
    }
    __syncthreads();
    unsigned short* dst = out + ((size_t)e * C + c0) * R + r0;
    const int cc = t >> 4;
    const int rv = t & 15;
#pragma unroll
    for (int i = 0; i < 4; i++) {
        int c = cc + 16 * i;
        ushort4 o;
        o.x = L[rv * 4 + 0][c];
        o.y = L[rv * 4 + 1][c];
        o.z = L[rv * 4 + 2][c];
        o.w = L[rv * 4 + 3][c];
        *(ushort4*)(dst + (size_t)c * R + rv * 4) = o;
    }
}

// ---- dispatch: slot assignment per (token, k); also records inverse map ----
__global__ void dispatch_kernel(const int* __restrict__ eidx, const float* __restrict__ ewt,
                                int* __restrict__ counts, int* __restrict__ row_token,
                                float* __restrict__ row_weight, int* __restrict__ slot_of) {
    int i = blockIdx.x * 256 + threadIdx.x;
    if (i < N_TOK * TOPK) {
        int e = eidx[i];
        int pos = atomicAdd(&counts[e], 1);
        int slot = -1;
        if (pos < CAP) {
            slot = e * CAP + pos;
            row_token[slot] = i >> 1;   // TOPK == 2
            row_weight[slot] = ewt[i];
        }
        slot_of[i] = slot;
    }
}

// ---- GEMM1: BM=128, BN=64(f). gate/value fused, silu*mul epilogue -> hidden bf16 ----
// Wave tile: 64m x 32n for BOTH gate and value -> 64 AGPR acc, 3 blocks/CU.
// Staging per K=32 iter: A 8KB + B1 4KB + B2 4KB = 16KB per 2.1 MFLOP (131 FLOP/B).
__global__ __launch_bounds__(256, 3)
void gemm1_kernel(const unsigned short* __restrict__ xb, const unsigned short* __restrict__ w1t,
                  const unsigned short* __restrict__ w2t, const int* __restrict__ counts,
                  const int* __restrict__ row_token, unsigned short* __restrict__ hidden) {
    const int e = blockIdx.z;
    const int r0 = blockIdx.y * 128;
    if (r0 >= counts[e]) return;
    const int f0 = blockIdx.x * 64;

    __shared__ unsigned short lA[128 * 32];   // 8 KB
    __shared__ unsigned short lB1[64 * 32];   // 4 KB
    __shared__ unsigned short lB2[64 * 32];   // 4 KB

    const int t = threadIdx.x;
    const int lane = t & 63;
    const int wave = t >> 6;

    // staging: XOR-swizzled source chunk (row-pair selector) — 0 bank conflicts (R2)
    const int rstage = t >> 2;                       // 0..63
    const int cs = (t & 3) ^ ((rstage >> 1) & 3);
    const int kbyte = cs * 16;

    const int tok0 = row_token[e * CAP + r0 + rstage];
    const int tok1 = row_token[e * CAP + r0 + 64 + rstage];
    const char* pA0 = (const char*)(xb + (size_t)tok0 * DM) + kbyte;
    const char* pA1 = (const char*)(xb + (size_t)tok1 * DM) + kbyte;
    const char* pB1 = (const char*)(w1t + ((size_t)e * DFF + f0 + rstage) * DM) + kbyte;
    const char* pB2 = (const char*)(w2t + ((size_t)e * DFF + f0 + rstage) * DM) + kbyte;

    char* lAp = (char*)lA + t * 16;
    char* lB1p = (char*)lB1 + t * 16;
    char* lB2p = (char*)lB2 + t * 16;

    const int mw = (wave & 1) * 64;
    const int nw = (wave >> 1) * 32;
    const int l15 = lane & 15;
    const int lq = lane >> 4;
    const int swz = (l15 >> 1) & 3;
    const unsigned short* aBase  = lA  + (mw + l15) * 32 + ((lq ^ swz) * 8);
    const unsigned short* b1Base = lB1 + (nw + l15) * 32 + ((lq ^ swz) * 8);
    const unsigned short* b2Base = lB2 + (nw + l15) * 32 + ((lq ^ swz) * 8);

    f32x4 accG[4][2];
    f32x4 accV[4][2];
#pragma unroll
    for (int i = 0; i < 4; i++)
#pragma unroll
        for (int j = 0; j < 2; j++) {
            accG[i][j] = (f32x4){0.f, 0.f, 0.f, 0.f};
            accV[i][j] = (f32x4){0.f, 0.f, 0.f, 0.f};
        }

    for (int k0 = 0; k0 < DM; k0 += 32) {
        glds16(pA0, lAp);  glds16(pA1, lAp + 4096);
        glds16(pB1, lB1p);
        glds16(pB2, lB2p);
        pA0 += 64; pA1 += 64; pB1 += 64; pB2 += 64;
        __syncthreads();

        bf16x8 a[4], b1[2], b2[2];
#pragma unroll
        for (int i = 0; i < 4; i++) a[i] = *(const bf16x8*)(aBase + i * 512);
#pragma unroll
        for (int j = 0; j < 2; j++) {
            b1[j] = *(const bf16x8*)(b1Base + j * 512);
            b2[j] = *(const bf16x8*)(b2Base + j * 512);
        }
#pragma unroll
        for (int i = 0; i < 4; i++)
#pragma unroll
            for (int j = 0; j < 2; j++) {
                accG[i][j] = __builtin_amdgcn_mfma_f32_16x16x32_bf16(a[i], b1[j], accG[i][j], 0, 0, 0);
                accV[i][j] = __builtin_amdgcn_mfma_f32_16x16x32_bf16(a[i], b2[j], accV[i][j], 0, 0, 0);
            }
        __syncthreads();
    }

    const size_t hbase = ((size_t)e * CAP + r0) * DFF + f0;
#pragma unroll
    for (int i = 0; i < 4; i++)
#pragma unroll
        for (int j = 0; j < 2; j++)
#pragma unroll
            for (int r = 0; r < 4; r++) {
                int m = mw + i * 16 + lq * 4 + r;
                int n = nw + j * 16 + l15;
                float g = accG[i][j][r];
                float v = accV[i][j][r];
                float h = (g / (1.f + __expf(-g))) * v;
                hidden[hbase + (size_t)m * DFF + n] = f2bf(h);
            }
}

// ---- GEMM2: out_rows[slot] = (hidden @ w3^T) * row_weight, bf16, no atomics ----
__global__ __launch_bounds__(256, 3)
void gemm2_kernel(const unsigned short* __restrict__ hidden, const unsigned short* __restrict__ w3t,
                  const int* __restrict__ counts, const float* __restrict__ row_weight,
                  unsigned short* __restrict__ out_rows) {
    const int e = blockIdx.z;
    const int r0 = blockIdx.y * 128;
    if (r0 >= counts[e]) return;
    const int d0 = blockIdx.x * 128;

    __shared__ unsigned short lA[128 * 32];
    __shared__ unsigned short lB[128 * 32];

    const int t = threadIdx.x;
    const int lane = t & 63;
    const int wave = t >> 6;

    const int rstage = t >> 2;
    const int cs = (t & 3) ^ ((rstage >> 1) & 3);
    const int kbyte = cs * 16;

    const char* pA0 = (const char*)(hidden + ((size_t)e * CAP + r0 + rstage) * DFF) + kbyte;
    const char* pA1 = pA0 + (size_t)64 * DFF * 2;
    const char* pB0 = (const char*)(w3t + ((size_t)e * DM + d0 + rstage) * DFF) + kbyte;
    const char* pB1 = pB0 + (size_t)64 * DFF * 2;

    char* lAp = (char*)lA + t * 16;
    char* lBp = (char*)lB + t * 16;

    const int mw = (wave & 1) * 64;
    const int nw = (wave >> 1) * 64;
    const int l15 = lane & 15;
    const int lq = lane >> 4;
    const int swz = (l15 >> 1) & 3;
    const unsigned short* aBase = lA + (mw + l15) * 32 + ((lq ^ swz) * 8);
    const unsigned short* bBase = lB + (nw + l15) * 32 + ((lq ^ swz) * 8);

    f32x4 acc[4][4];
#pragma unroll
    for (int i = 0; i < 4; i++)
#pragma unroll
        for (int j = 0; j < 4; j++) acc[i][j] = (f32x4){0.f, 0.f, 0.f, 0.f};

    for (int k0 = 0; k0 < DFF; k0 += 32) {
        glds16(pA0, lAp);  glds16(pA1, lAp + 4096);
        glds16(pB0, lBp);  glds16(pB1, lBp + 4096);
        pA0 += 64; pA1 += 64; pB0 += 64; pB1 += 64;
        __syncthreads();

        bf16x8 a[4], b[4];
#pragma unroll
        for (int i = 0; i < 4; i++) {
            a[i] = *(const bf16x8*)(aBase + i * 512);
            b[i] = *(const bf16x8*)(bBase + i * 512);
        }
#pragma unroll
        for (int i = 0; i < 4; i++)
#pragma unroll
            for (int j = 0; j < 4; j++)
                acc[i][j] = __builtin_amdgcn_mfma_f32_16x16x32_bf16(a[i], b[j], acc[i][j], 0, 0, 0);
        __syncthreads();
    }

    const float* rw = row_weight + e * CAP + r0;
#pragma unroll
    for (int i = 0; i < 4; i++)
#pragma unroll
        for (int r = 0; r < 4; r++) {
            int m = mw + i * 16 + lq * 4 + r;
            float w = rw[m];   // 0 for padding rows (memset) -> writes 0
            unsigned short* orow = out_rows + ((size_t)(e * CAP + r0 + m)) * DM + d0 + nw + l15;
#pragma unroll
            for (int j = 0; j < 4; j++)
                orow[j * 16] = f2bf(acc[i][j][r] * w);
        }
}

// ---- combine: out[tok] = out_rows[slot0] + out_rows[slot1] (pre-weighted) ----
__global__ void combine_kernel(const int* __restrict__ slot_of,
                               const unsigned short* __restrict__ out_rows,
                               float4* __restrict__ out) {
    const int tok = blockIdx.x;
    const int t = threadIdx.x;
    const int s0 = slot_of[2 * tok];
    const int s1 = slot_of[2 * tok + 1];
    float4 acc = {0.f, 0.f, 0.f, 0.f};
    if (s0 >= 0) {
        ushort4 r = ((const ushort4*)(out_rows + (size_t)s0 * DM))[t];
        acc.x += bf2f(r.x); acc.y += bf2f(r.y); acc.z += bf2f(r.z); acc.w += bf2f(r.w);
    }
    if (s1 >= 0) {
        ushort4 r = ((const ushort4*)(out_rows + (size_t)s1 * DM))[t];
        acc.x += bf2f(r.x); acc.y += bf2f(r.y); acc.z += bf2f(r.z); acc.w += bf2f(r.w);
    }
    out[(size_t)tok * (DM / 4) + t] = acc;
}

extern "C" void kernel_launch(void* const* d_in, const int* in_sizes, int n_in,
                              void* d_out, int out_size, void* d_ws, size_t ws_size,
                              hipStream_t stream) {
    const float* x = (const float*)d_in[0];
    const int* eidx = (const int*)d_in[1];
    const float* ewt = (const float*)d_in[2];
    const float* w1 = (const float*)d_in[3];
    const float* w2 = (const float*)d_in[4];
    const float* w3 = (const float*)d_in[5];
    float* out = (float*)d_out;

    char* ws = (char*)d_ws;
    size_t off = 0;
    auto alloc = [&](size_t b) { size_t o = off; off += (b + 255) & ~(size_t)255; return o; };
    int*   counts     = (int*)(ws + alloc(N_EXP * 4));
    int*   row_token  = (int*)(ws + alloc((size_t)N_EXP * CAP * 4));
    float* row_weight = (float*)(ws + alloc((size_t)N_EXP * CAP * 4));
    size_t hdr_end = off;  // memset range: counts + row_token + row_weight
    int*   slot_of    = (int*)(ws + alloc((size_t)N_TOK * TOPK * 4));  // fully written by dispatch
    unsigned short* xb  = (unsigned short*)(ws + alloc((size_t)N_TOK * DM * 2));
    unsigned short* w1t = (unsigned short*)(ws + alloc((size_t)N_EXP * DFF * DM * 2));
    unsigned short* w2t = (unsigned short*)(ws + alloc((size_t)N_EXP * DFF * DM * 2));
    unsigned short* w3t = (unsigned short*)(ws + alloc((size_t)N_EXP * DM * DFF * 2));
    unsigned short* hidden = (unsigned short*)(ws + alloc((size_t)N_EXP * CAP * DFF * 2));
    // out_rows (48 MB) aliases w1t+w2t (64 MB) — both dead after gemm1 completes.
    unsigned short* out_rows = w1t;
    (void)ws_size; (void)in_sizes; (void)n_in;

    hipMemsetAsync(ws, 0, hdr_end, stream);  // counts + row_token + row_weight

    cvt_x_kernel<<<(N_TOK * DM / 4) / 256, 256, 0, stream>>>((const float4*)x, (ushort4*)xb);
    transpose_cvt64_kernel<<<dim3(DFF / 64, DM / 64, 16), 256, 0, stream>>>(w1, w2, w1t, w2t, DM, DFF);
    transpose_cvt64_kernel<<<dim3(DM / 64, DFF / 64, 8), 256, 0, stream>>>(w3, w3, w3t, w3t, DFF, DM);
    dispatch_kernel<<<(N_TOK * TOPK) / 256, 256, 0, stream>>>(eidx, ewt, counts, row_token, row_weight, slot_of);

    gemm1_kernel<<<dim3(DFF / 64, CAP / 128, N_EXP), 256, 0, stream>>>(xb, w1t, w2t, counts, row_token, hidden);
    gemm2_kernel<<<dim3(DM / 128, CAP / 128, N_EXP), 256, 0, stream>>>(hidden, w3t, counts, row_weight, out_rows);
    combine_kernel<<<N_TOK, 256, 0, stream>>>(slot_of, out_rows, (float4*)out);
}